// Round 15
// baseline (249.965 us; speedup 1.0000x reference)
//
#include <hip/hip_runtime.h>

// DMT skeletonize: exact separable squared-EDT + 26-neighborhood local max.
// img (4,1,160,160,160) f32. All work on squared distances (sqrt elision is
// decision-identical: values are exact integers < 2^24 or the 1e12 sentinel).
// INF arithmetic: 1e12f + r^2 rounds back to 1e12f for r^2 < 32768 in fp32
// (per-pass r^2 <= 159^2 = 25281) -> bit-exact vs the reference.

#define INF_F 1.0e12f

constexpr int NX = 160, NY = 160, NZ = 160, NB = 4;
constexpr int VOL   = NX * NY * NZ;        // 4,096,000 per batch
constexpr int TOTAL = NB * VOL;            // 16,384,000
constexpr int NROWS = NB * NZ * NY;        // 102,400 x-rows
constexpr int BLK   = 256;

__device__ inline float4 f4max(float4 a, float4 b) {
    return make_float4(fmaxf(a.x, b.x), fmaxf(a.y, b.y),
                       fmaxf(a.z, b.z), fmaxf(a.w, b.w));
}

__device__ inline float edt1d_combine(int x, int lz, int rz) {
    // lz: nearest zero-site <= x (big-negative sentinel); rz: >= x (big-pos).
    float dl2 = (lz >= 0)   ? (float)((x - lz) * (x - lz)) : INF_F;
    float dr2 = (rz < 1000) ? (float)((rz - x) * (rz - x)) : INF_F;
    return fminf(dl2, dr2);
}

// ---------------------------------------------------------------------------
// Pass 1 (along X): exact binary 1-D EDT via ballot masks + bit scans.
// One wave per row of 160 (chunks 64/64/32). Nearest zero-site left/right of
// each lane = nearest set bit in the 64-bit ballot mask -- pure VALU bit ops,
// no cross-lane dependency chains. Zero-site := img > 0.5.
__global__ void edt_pass_x_ballot(const float* __restrict__ img,
                                  float* __restrict__ out) {
    int gw = blockIdx.x * (BLK / 64) + (threadIdx.x >> 6);   // wave id = row
    if (gw >= NROWS) return;                 // wave-uniform exit
    int lane = threadIdx.x & 63;
    int b = gw * NX;

    float a0 = img[b + lane];
    float a1 = img[b + 64 + lane];
    float a2 = (lane < 32) ? img[b + 128 + lane] : 0.0f;

    unsigned long long m0 = __ballot(a0 > 0.5f);
    unsigned long long m1 = __ballot(a1 > 0.5f);
    unsigned long long m2 = __ballot((lane < 32) && (a2 > 0.5f)); // bits 0..31

    const int NEG = -1048576, POS = 1048576;
    unsigned long long loMask = (~0ULL) >> (63 - lane);   // bits 0..lane
    unsigned long long hiMask = (~0ULL) << lane;          // bits lane..63

    // ---- chunk 0 (p = lane) ----
    unsigned long long t;
    t = m0 & loMask;
    int lz0 = t ? (63 - __clzll(t)) : NEG;
    t = m0 & hiMask;
    int rz0 = t ? (__ffsll(t) - 1)
                : (m1 ? (64 + __ffsll(m1) - 1)
                      : (m2 ? (128 + __ffsll(m2) - 1) : POS));

    // ---- chunk 1 (p = 64 + lane) ----
    t = m1 & loMask;
    int lz1 = t ? (64 + 63 - __clzll(t))
                : (m0 ? (63 - __clzll(m0)) : NEG);
    t = m1 & hiMask;
    int rz1 = t ? (64 + __ffsll(t) - 1)
                : (m2 ? (128 + __ffsll(m2) - 1) : POS);

    // ---- chunk 2 (p = 128 + lane, lanes 0..31) ----
    t = m2 & loMask;
    int lz2 = t ? (128 + 63 - __clzll(t))
                : (m1 ? (64 + 63 - __clzll(m1))
                      : (m0 ? (63 - __clzll(m0)) : NEG));
    t = m2 & hiMask;
    int rz2 = t ? (128 + __ffsll(t) - 1) : POS;

    out[b + lane]      = edt1d_combine(lane,       lz0, rz0);
    out[b + 64 + lane] = edt1d_combine(64 + lane,  lz1, rz1);
    if (lane < 32)
        out[b + 128 + lane] = edt1d_combine(128 + lane, lz2, rz2);
}

// ---------------------------------------------------------------------------
// Passes 2/3 (axis stride S, length 160), 4 voxels per thread, radii in
// BATCHES OF 4: one break check per batch, then up to 8 independent float4
// loads issued back-to-back (deep MLP; addresses are data-independent).
// Exact: we skip the batch starting at r=base+1 only when (base+1)^2 >=
// max(cur) -- every skipped candidate is >= (base+1)^2 >= each component
// (g >= 0). Extra in-batch candidates are always-valid candidates.
template <int S>
__global__ void edt_pass_axis4b(const float* __restrict__ g,
                                float* __restrict__ out) {
    int tid = blockIdx.x * BLK + threadIdx.x;
    if (tid >= TOTAL / 4) return;
    int idx4 = tid * 4;                     // 4 consecutive x, same axis coord
    int c = (idx4 / S) % 160;
    float4 cur = *reinterpret_cast<const float4*>(g + idx4);

    for (int base = 0; base < 159; base += 4) {
        float m = fmaxf(fmaxf(cur.x, cur.y), fmaxf(cur.z, cur.w));
        float rb2 = (float)((base + 1) * (base + 1));
        if (rb2 >= m) break;                // all 4 converged (exact)
        #pragma unroll
        for (int k = 1; k <= 4; ++k) {
            int r = base + k;               // r = base+1 .. base+4
            float r2 = (float)(r * r);
            if (c - r >= 0) {
                float4 u = *reinterpret_cast<const float4*>(g + idx4 - r * S);
                cur.x = fminf(cur.x, u.x + r2); cur.y = fminf(cur.y, u.y + r2);
                cur.z = fminf(cur.z, u.z + r2); cur.w = fminf(cur.w, u.w + r2);
            }
            if (c + r < 160) {
                float4 d = *reinterpret_cast<const float4*>(g + idx4 + r * S);
                cur.x = fminf(cur.x, d.x + r2); cur.y = fminf(cur.y, d.y + r2);
                cur.z = fminf(cur.z, d.z + r2); cur.w = fminf(cur.w, d.w + r2);
            }
        }
    }
    *reinterpret_cast<float4*>(out + idx4) = cur;
}

// ---------------------------------------------------------------------------
// Skeleton v3: 4x2x2 tile (16 outputs) per thread. All 48 window loads issued
// up-front into statically-indexed arrays -> deep MLP; replicate-clamp
// boundaries (decision-identical to skip-OOB for a max window).
constexpr int NX4 = NX / 4, NY2 = NY / 2, NZ2 = NZ / 2;
constexpr int NTILE = NB * NZ2 * NY2 * NX4;   // 1,024,000 threads

__global__ void skel_kernel3(const float* __restrict__ d2,
                             const float* __restrict__ img,
                             float* __restrict__ out) {
    int tid = blockIdx.x * BLK + threadIdx.x;
    if (tid >= NTILE) return;
    int x4 = (tid % NX4) * 4;
    int t  = tid / NX4;
    int y  = (t % NY2) * 2;
    t /= NY2;
    int z  = (t % NZ2) * 2;
    int b  = t / NZ2;

    int base = ((b * NZ + z) * NY + y) * NX;
    const int yo[4] = { (y > 0) ? -NX : 0, 0, NX,
                        (y + 2 < NY) ? 2 * NX : NX };
    const int zo[4] = { (z > 0) ? -NX * NY : 0, 0, NX * NY,
                        (z + 2 < NZ) ? 2 * NX * NY : NX * NY };
    const int xl = (x4 > 0) ? x4 - 1 : 0;
    const int xr = (x4 + 4 < NX) ? x4 + 4 : NX - 1;

    float4 m[4][4];
    float  L[4][4], R[4][4];
    #pragma unroll
    for (int iz = 0; iz < 4; ++iz) {
        #pragma unroll
        for (int iy = 0; iy < 4; ++iy) {
            const float* row = d2 + base + zo[iz] + yo[iy];
            m[iz][iy] = *reinterpret_cast<const float4*>(row + x4);
            L[iz][iy] = row[xl];
            R[iz][iy] = row[xr];
        }
    }

    float4 h[4][4];
    #pragma unroll
    for (int iz = 0; iz < 4; ++iz) {
        #pragma unroll
        for (int iy = 0; iy < 4; ++iy) {
            float4 v = m[iz][iy];
            h[iz][iy] = make_float4(
                fmaxf(fmaxf(L[iz][iy], v.x), v.y),
                fmaxf(fmaxf(v.x, v.y), v.z),
                fmaxf(fmaxf(v.y, v.z), v.w),
                fmaxf(fmaxf(v.z, v.w), R[iz][iy]));
        }
    }

    float4 cm[4][2];
    #pragma unroll
    for (int iz = 0; iz < 4; ++iz) {
        cm[iz][0] = f4max(f4max(h[iz][0], h[iz][1]), h[iz][2]);
        cm[iz][1] = f4max(f4max(h[iz][1], h[iz][2]), h[iz][3]);
    }

    #pragma unroll
    for (int oz = 0; oz < 2; ++oz) {
        #pragma unroll
        for (int oy = 0; oy < 2; ++oy) {
            float4 mx = f4max(f4max(cm[oz][oy], cm[oz + 1][oy]), cm[oz + 2][oy]);
            float4 ctr = m[oz + 1][oy + 1];
            int o = base + oz * NX * NY + oy * NX + x4;
            float4 iv = *reinterpret_cast<const float4*>(img + o);
            float4 ov;
            ov.x = (ctr.x >= mx.x && ctr.x > 0.0f) ? iv.x : 0.0f;
            ov.y = (ctr.y >= mx.y && ctr.y > 0.0f) ? iv.y : 0.0f;
            ov.z = (ctr.z >= mx.z && ctr.z > 0.0f) ? iv.z : 0.0f;
            ov.w = (ctr.w >= mx.w && ctr.w > 0.0f) ? iv.w : 0.0f;
            *reinterpret_cast<float4*>(out + o) = ov;
        }
    }
}

// ---------------------------------------------------------------------------
extern "C" void kernel_launch(void* const* d_in, const int* in_sizes, int n_in,
                              void* d_out, int out_size, void* d_ws, size_t ws_size,
                              hipStream_t stream) {
    const float* img = (const float*)d_in[0];
    float* outp = (float*)d_out;
    float* ws   = (float*)d_ws;             // needs >= TOTAL*4 = 65.5 MB

    int gridRows = (NROWS + 3) / 4;               // X-pass: 4 rows/block
    int grid4    = (TOTAL / 4 + BLK - 1) / BLK;   // 16,000 blocks
    int gridT    = (NTILE + BLK - 1) / BLK;       // 4,000 blocks

    // K1: X-pass (ballot-based binary EDT): img -> ws
    edt_pass_x_ballot<<<gridRows, BLK, 0, stream>>>(img, ws);
    // K2: Y-pass (stride 160), batched radii: ws -> d_out (scratch)
    edt_pass_axis4b<NX><<<grid4, BLK, 0, stream>>>(ws, outp);
    // K3: Z-pass (stride 25600), batched radii: d_out -> ws
    edt_pass_axis4b<NX * NY><<<grid4, BLK, 0, stream>>>(outp, ws);
    // K4: skeleton + multiply, 4x2x2 tile/thread: (ws = final d2, img) -> d_out
    skel_kernel3<<<gridT, BLK, 0, stream>>>(ws, img, outp);
}

// Round 16
// 218.367 us; speedup vs baseline: 1.1447x; 1.1447x over previous
//
#include <hip/hip_runtime.h>

// DMT skeletonize: exact separable squared-EDT + 26-neighborhood local max.
// img (4,1,160,160,160) f32. All work on squared distances (sqrt elision is
// decision-identical: values are exact integers < 2^24 or the 1e12 sentinel).
// INF arithmetic: 1e12f + r^2 rounds back to 1e12f for r^2 < 32768 in fp32
// (per-pass r^2 <= 159^2 = 25281) -> bit-exact vs the reference.

#define INF_F 1.0e12f

constexpr int NX = 160, NY = 160, NZ = 160, NB = 4;
constexpr int VOL   = NX * NY * NZ;        // 4,096,000 per batch
constexpr int TOTAL = NB * VOL;            // 16,384,000
constexpr int NROWS = NB * NZ * NY;        // 102,400 x-rows
constexpr int BLK   = 256;

__device__ inline float4 f4max(float4 a, float4 b) {
    return make_float4(fmaxf(a.x, b.x), fmaxf(a.y, b.y),
                       fmaxf(a.z, b.z), fmaxf(a.w, b.w));
}

__device__ inline float edt1d_combine(int x, int lz, int rz) {
    // lz: nearest zero-site <= x (big-negative sentinel); rz: >= x (big-pos).
    float dl2 = (lz >= 0)   ? (float)((x - lz) * (x - lz)) : INF_F;
    float dr2 = (rz < 1000) ? (float)((rz - x) * (rz - x)) : INF_F;
    return fminf(dl2, dr2);
}

// ---------------------------------------------------------------------------
// Pass 1 (along X): exact binary 1-D EDT via ballot masks + bit scans.
// One wave per row of 160 (chunks 64/64/32). Nearest zero-site left/right of
// each lane = nearest set bit in the 64-bit ballot mask -- pure VALU bit ops,
// no cross-lane dependency chains. Zero-site := img > 0.5.
__global__ void edt_pass_x_ballot(const float* __restrict__ img,
                                  float* __restrict__ out) {
    int gw = blockIdx.x * (BLK / 64) + (threadIdx.x >> 6);   // wave id = row
    if (gw >= NROWS) return;                 // wave-uniform exit
    int lane = threadIdx.x & 63;
    int b = gw * NX;

    float a0 = img[b + lane];
    float a1 = img[b + 64 + lane];
    float a2 = (lane < 32) ? img[b + 128 + lane] : 0.0f;

    unsigned long long m0 = __ballot(a0 > 0.5f);
    unsigned long long m1 = __ballot(a1 > 0.5f);
    unsigned long long m2 = __ballot((lane < 32) && (a2 > 0.5f)); // bits 0..31

    const int NEG = -1048576, POS = 1048576;
    unsigned long long loMask = (~0ULL) >> (63 - lane);   // bits 0..lane
    unsigned long long hiMask = (~0ULL) << lane;          // bits lane..63

    // ---- chunk 0 (p = lane) ----
    unsigned long long t;
    t = m0 & loMask;
    int lz0 = t ? (63 - __clzll(t)) : NEG;
    t = m0 & hiMask;
    int rz0 = t ? (__ffsll(t) - 1)
                : (m1 ? (64 + __ffsll(m1) - 1)
                      : (m2 ? (128 + __ffsll(m2) - 1) : POS));

    // ---- chunk 1 (p = 64 + lane) ----
    t = m1 & loMask;
    int lz1 = t ? (64 + 63 - __clzll(t))
                : (m0 ? (63 - __clzll(m0)) : NEG);
    t = m1 & hiMask;
    int rz1 = t ? (64 + __ffsll(t) - 1)
                : (m2 ? (128 + __ffsll(m2) - 1) : POS);

    // ---- chunk 2 (p = 128 + lane, lanes 0..31) ----
    t = m2 & loMask;
    int lz2 = t ? (128 + 63 - __clzll(t))
                : (m1 ? (64 + 63 - __clzll(m1))
                      : (m0 ? (63 - __clzll(m0)) : NEG));
    t = m2 & hiMask;
    int rz2 = t ? (128 + __ffsll(t) - 1) : POS;

    out[b + lane]      = edt1d_combine(lane,       lz0, rz0);
    out[b + 64 + lane] = edt1d_combine(64 + lane,  lz1, rz1);
    if (lane < 32)
        out[b + 128 + lane] = edt1d_combine(128 + lane, lz2, rz2);
}

// ---------------------------------------------------------------------------
// Passes 2/3: LDS-staged axis pass. One block (640 thr) owns a tile of
// [160 along-axis] x [16 x-floats]; each thread (c, xg) stages its own
// float4 once (coalesced 64B rows; global read exactly once -> no
// over-fetch), then outward-searches against LDS rows c+-r with a
// per-thread exact break (r^2 >= max of own 4 components; g >= 0).
// LDS row stride 20 floats: 16B-aligned float4s, 2-way bank alias only.
//   Y-pass: S = NX (160),   OSM = NX*NY (o%160 = z selects the z-plane)
//   Z-pass: S = NX*NY,      OSM = NX    (o%160 = y selects the y-row)
constexpr int XT = 16;                     // x-tile width (floats)
constexpr int NXT = NX / XT;               // 10 x-tiles
constexpr int LROW = 20;                   // padded LDS row stride (floats)

template <int S, int OSM>
__global__ __launch_bounds__(640)
void edt_pass_axis_lds(const float* __restrict__ g, float* __restrict__ out) {
    __shared__ float tile[160 * LROW];     // 12.8 KB
    int t  = blockIdx.x;
    int xt = t % NXT;
    int o  = t / NXT;                      // Y: b*NZ+z ; Z: b*NY+y
    int base = (o / 160) * VOL + (o % 160) * OSM + xt * XT;

    int tid = threadIdx.x;                 // 0..639
    int xg  = tid & 3;                     // float4 slot within 16-float strip
    int c   = tid >> 2;                    // axis coordinate 0..159

    int gidx = base + c * S + xg * 4;
    float4 cur = *reinterpret_cast<const float4*>(g + gidx);
    *reinterpret_cast<float4*>(&tile[c * LROW + xg * 4]) = cur;
    __syncthreads();

    float r2 = 1.0f, odd = 1.0f;
    for (int r = 1; r < 160; ++r) {
        float m = fmaxf(fmaxf(cur.x, cur.y), fmaxf(cur.z, cur.w));
        if (r2 >= m) break;                // exact: all skipped cands >= r^2
        int cl = c - r, ch = c + r;
        if (cl >= 0) {
            float4 u = *reinterpret_cast<const float4*>(&tile[cl * LROW + xg * 4]);
            cur.x = fminf(cur.x, u.x + r2); cur.y = fminf(cur.y, u.y + r2);
            cur.z = fminf(cur.z, u.z + r2); cur.w = fminf(cur.w, u.w + r2);
        }
        if (ch < 160) {
            float4 d = *reinterpret_cast<const float4*>(&tile[ch * LROW + xg * 4]);
            cur.x = fminf(cur.x, d.x + r2); cur.y = fminf(cur.y, d.y + r2);
            cur.z = fminf(cur.z, d.z + r2); cur.w = fminf(cur.w, d.w + r2);
        }
        odd += 2.0f; r2 += odd;            // (r+1)^2 = r^2 + (2r+1)
    }
    *reinterpret_cast<float4*>(out + gidx) = cur;
}

// ---------------------------------------------------------------------------
// Skeleton v3: 4x2x2 tile (16 outputs) per thread. All 48 window loads issued
// up-front into statically-indexed arrays -> deep MLP; replicate-clamp
// boundaries (decision-identical to skip-OOB for a max window).
constexpr int NX4 = NX / 4, NY2 = NY / 2, NZ2 = NZ / 2;
constexpr int NTILE = NB * NZ2 * NY2 * NX4;   // 1,024,000 threads

__global__ void skel_kernel3(const float* __restrict__ d2,
                             const float* __restrict__ img,
                             float* __restrict__ out) {
    int tid = blockIdx.x * BLK + threadIdx.x;
    if (tid >= NTILE) return;
    int x4 = (tid % NX4) * 4;
    int t  = tid / NX4;
    int y  = (t % NY2) * 2;
    t /= NY2;
    int z  = (t % NZ2) * 2;
    int b  = t / NZ2;

    int base = ((b * NZ + z) * NY + y) * NX;
    const int yo[4] = { (y > 0) ? -NX : 0, 0, NX,
                        (y + 2 < NY) ? 2 * NX : NX };
    const int zo[4] = { (z > 0) ? -NX * NY : 0, 0, NX * NY,
                        (z + 2 < NZ) ? 2 * NX * NY : NX * NY };
    const int xl = (x4 > 0) ? x4 - 1 : 0;
    const int xr = (x4 + 4 < NX) ? x4 + 4 : NX - 1;

    float4 m[4][4];
    float  L[4][4], R[4][4];
    #pragma unroll
    for (int iz = 0; iz < 4; ++iz) {
        #pragma unroll
        for (int iy = 0; iy < 4; ++iy) {
            const float* row = d2 + base + zo[iz] + yo[iy];
            m[iz][iy] = *reinterpret_cast<const float4*>(row + x4);
            L[iz][iy] = row[xl];
            R[iz][iy] = row[xr];
        }
    }

    float4 h[4][4];
    #pragma unroll
    for (int iz = 0; iz < 4; ++iz) {
        #pragma unroll
        for (int iy = 0; iy < 4; ++iy) {
            float4 v = m[iz][iy];
            h[iz][iy] = make_float4(
                fmaxf(fmaxf(L[iz][iy], v.x), v.y),
                fmaxf(fmaxf(v.x, v.y), v.z),
                fmaxf(fmaxf(v.y, v.z), v.w),
                fmaxf(fmaxf(v.z, v.w), R[iz][iy]));
        }
    }

    float4 cm[4][2];
    #pragma unroll
    for (int iz = 0; iz < 4; ++iz) {
        cm[iz][0] = f4max(f4max(h[iz][0], h[iz][1]), h[iz][2]);
        cm[iz][1] = f4max(f4max(h[iz][1], h[iz][2]), h[iz][3]);
    }

    #pragma unroll
    for (int oz = 0; oz < 2; ++oz) {
        #pragma unroll
        for (int oy = 0; oy < 2; ++oy) {
            float4 mx = f4max(f4max(cm[oz][oy], cm[oz + 1][oy]), cm[oz + 2][oy]);
            float4 ctr = m[oz + 1][oy + 1];
            int o = base + oz * NX * NY + oy * NX + x4;
            float4 iv = *reinterpret_cast<const float4*>(img + o);
            float4 ov;
            ov.x = (ctr.x >= mx.x && ctr.x > 0.0f) ? iv.x : 0.0f;
            ov.y = (ctr.y >= mx.y && ctr.y > 0.0f) ? iv.y : 0.0f;
            ov.z = (ctr.z >= mx.z && ctr.z > 0.0f) ? iv.z : 0.0f;
            ov.w = (ctr.w >= mx.w && ctr.w > 0.0f) ? iv.w : 0.0f;
            *reinterpret_cast<float4*>(out + o) = ov;
        }
    }
}

// ---------------------------------------------------------------------------
extern "C" void kernel_launch(void* const* d_in, const int* in_sizes, int n_in,
                              void* d_out, int out_size, void* d_ws, size_t ws_size,
                              hipStream_t stream) {
    const float* img = (const float*)d_in[0];
    float* outp = (float*)d_out;
    float* ws   = (float*)d_ws;             // needs >= TOTAL*4 = 65.5 MB

    int gridRows = (NROWS + 3) / 4;               // X-pass: 4 rows/block
    int gridAx   = NB * 160 * NXT;                // 6,400 tile-blocks
    int gridT    = (NTILE + BLK - 1) / BLK;       // 4,000 blocks

    // K1: X-pass (ballot-based binary EDT): img -> ws
    edt_pass_x_ballot<<<gridRows, BLK, 0, stream>>>(img, ws);
    // K2: Y-pass (LDS-staged, S=160): ws -> d_out (scratch)
    edt_pass_axis_lds<NX, NX * NY><<<gridAx, 640, 0, stream>>>(ws, outp);
    // K3: Z-pass (LDS-staged, S=25600): d_out -> ws
    edt_pass_axis_lds<NX * NY, NX><<<gridAx, 640, 0, stream>>>(outp, ws);
    // K4: skeleton + multiply, 4x2x2 tile/thread: (ws = final d2, img) -> d_out
    skel_kernel3<<<gridT, BLK, 0, stream>>>(ws, img, outp);
}